// Round 3
// baseline (316.130 us; speedup 1.0000x reference)
//
#include <hip/hip_runtime.h>

// WindowAttention B=8 H=W=256 C=96 ws=8 heads=4 hd=24 — fp16 MFMA, transpose-world.
// One block (4 waves) per window; wave = head in attention phase.

typedef _Float16 f16;
typedef f16 f16x8 __attribute__((ext_vector_type(8)));
typedef f16 f16x4 __attribute__((ext_vector_type(4)));
typedef float f32x4 __attribute__((ext_vector_type(4)));

#define MFMA16 __builtin_amdgcn_mfma_f32_16x16x32_f16

__global__ void cvt_weights(const float* __restrict__ qkv_w,
                            const float* __restrict__ proj_w,
                            f16* __restrict__ ws) {
    int i = blockIdx.x * 256 + threadIdx.x;
    if (i < 27648)      ws[i] = (f16)qkv_w[i];
    else if (i < 36864) ws[i] = (f16)proj_w[i - 27648];
}

// dynamic LDS layout (bytes)
#define OFF_XS   0        // f16[64*96]   12288   xs (phase0/1) / osb (O staging)
#define OFF_QQ   12288    // f16[64*128]  16384   q, head-padded, swizzled
#define OFF_QK   28672    // f16[64*128]  16384   k, head-padded, swizzled
#define OFF_VT   45056    // f16[4*32*64] 16384   v^T per head  | o2 f32[64*128] spans VT+PL
#define OFF_PL   61440    // f16[4*64*32] 16384   P chunk per wave
#define SMEM_BYTES 77824

__device__ __forceinline__ int qidx(int t, int o)         { return t*128 + (o ^ ((t&7)<<3)); }
__device__ __forceinline__ int vidx(int h, int d, int u)  { return (h*32+d)*64 + (u ^ ((d&7)<<3)); }
__device__ __forceinline__ int pidx(int wv, int t, int u) { return wv*2048 + t*32 + (u ^ ((t&3)<<3)); }
__device__ __forceinline__ int oidx(int t, int c)         { return t*128 + (c ^ ((t&7)<<3)); }

__global__ __launch_bounds__(256, 2) void winattn(
    const float* __restrict__ x,
    const f16*   __restrict__ qw,      // [288][96]
    const float* __restrict__ qkv_b,   // [288]
    const f16*   __restrict__ pw,      // [96][96]
    const float* __restrict__ proj_b,  // [96]
    float* __restrict__ out)
{
    extern __shared__ __align__(16) char smc[];
    f16* xs  = (f16*)(smc + OFF_XS);
    f16* osb = (f16*)(smc + OFF_XS);
    f16* qq  = (f16*)(smc + OFF_QQ);
    f16* qk  = (f16*)(smc + OFF_QK);
    f16* vt  = (f16*)(smc + OFF_VT);
    f16* pl  = (f16*)(smc + OFF_PL);
    float* o2 = (float*)(smc + OFF_VT);

    const int tid = threadIdx.x;
    const int wid = blockIdx.x;
    const int bb = wid >> 10, wh = (wid >> 5) & 31, ww = wid & 31;
    const size_t win_base = ((size_t)(bb*256 + wh*8)*256 + (size_t)(ww*8)) * 96;

    const int lane = tid & 63, w = tid >> 6;
    const int lr = lane & 15, lg = lane >> 4;

    // ---- zero K-pads (d=24..31) for qq/qk/vt (read by K=32 MFMAs in phase 2)
    {
        const f16x8 z8 = {0,0,0,0,0,0,0,0};
        const int tz = tid >> 2, hz = tid & 3;
        *(f16x8*)&qq[qidx(tz, hz*32 + 24)] = z8;
        *(f16x8*)&qk[qidx(tz, hz*32 + 24)] = z8;
        const int hv = tid >> 6, dv = 24 + ((tid >> 3) & 7), uo = (tid & 7) * 8;
        *(f16x8*)&vt[vidx(hv, dv, uo)] = z8;
    }
    // ---- phase 0: stage x -> fp16 LDS [t][96]
    #pragma unroll
    for (int it = 0; it < 6; ++it) {
        const int i = it*256 + tid;
        const int t = i / 24, c4 = i - t*24;
        const float4 v = *(const float4*)(x + win_base + (size_t)(((t>>3)<<8) + (t&7))*96 + c4*4);
        f16x4 hv4 = {(f16)v.x, (f16)v.y, (f16)v.z, (f16)v.w};
        *(f16x4*)&xs[t*96 + c4*4] = hv4;
    }
    __syncthreads();

    // ---- phase 1: qkvT[j][t] = sum_c qw[j][c] * x[t][c]   (wave w owns t-tile w)
    {
        const int t = 16*w + lr;
        f16x8 bx[3];
        #pragma unroll
        for (int kk = 0; kk < 3; ++kk)
            bx[kk] = *(const f16x8*)&xs[t*96 + kk*32 + lg*8];
        #pragma unroll
        for (int n = 0; n < 18; ++n) {
            const int j = 16*n + lr;
            f32x4 acc = {0.f,0.f,0.f,0.f};
            #pragma unroll
            for (int kk = 0; kk < 3; ++kk) {
                const f16x8 aw = *(const f16x8*)(qw + j*96 + kk*32 + lg*8);
                acc = MFMA16(aw, bx[kk], acc, 0, 0, 0);
            }
            const int j0 = 16*n + 4*lg;                 // reg-quad: channels j0..j0+3, token t
            const float4 b4 = *(const float4*)(qkv_b + j0);
            const float v0 = acc[0]+b4.x, v1 = acc[1]+b4.y, v2 = acc[2]+b4.z, v3 = acc[3]+b4.w;
            if (n < 6) {                                // q
                const int h = (unsigned)j0 / 24u, d0 = j0 - 24*h;
                f16x4 hv4 = {(f16)v0,(f16)v1,(f16)v2,(f16)v3};
                *(f16x4*)&qq[qidx(t, h*32 + d0)] = hv4;
            } else if (n < 12) {                        // k
                const int jk = j0 - 96;
                const int h = (unsigned)jk / 24u, d0 = jk - 24*h;
                f16x4 hv4 = {(f16)v0,(f16)v1,(f16)v2,(f16)v3};
                *(f16x4*)&qk[qidx(t, h*32 + d0)] = hv4;
            } else {                                    // v -> v^T (scalar, 6 tiles only)
                const int jv = j0 - 192;
                const int h = (unsigned)jv / 24u, d0 = jv - 24*h;
                vt[vidx(h, d0+0, t)] = (f16)v0;
                vt[vidx(h, d0+1, t)] = (f16)v1;
                vt[vidx(h, d0+2, t)] = (f16)v2;
                vt[vidx(h, d0+3, t)] = (f16)v3;
            }
        }
    }
    __syncthreads();

    // ---- phase 2: wave = head.  S^T = mfma(K, Q); in-reg softmax; O^T = mfma(V^T, P)
    {
        const int h = w;
        f16x8 af[4], bf[4];
        #pragma unroll
        for (int i = 0; i < 4; ++i) {
            af[i] = *(const f16x8*)&qk[qidx(16*i + lr, h*32 + lg*8)];
            bf[i] = *(const f16x8*)&qq[qidx(16*i + lr, h*32 + lg*8)];
        }
        f32x4 st[4][4];                         // S^T tile (un,tn): u=16un+4lg+r, t=16tn+lr
        #pragma unroll
        for (int un = 0; un < 4; ++un)
            #pragma unroll
            for (int tn = 0; tn < 4; ++tn)
                st[un][tn] = MFMA16(af[un], bf[tn], (f32x4){0.f,0.f,0.f,0.f}, 0,0,0);

        const float kE = 0.29448889f;           // 24^-0.5 * log2(e)
        float mk[4], rs[4];
        #pragma unroll
        for (int tn = 0; tn < 4; ++tn) {
            float m = st[0][tn][0];
            #pragma unroll
            for (int un = 0; un < 4; ++un)
                #pragma unroll
                for (int r = 0; r < 4; ++r)
                    m = fmaxf(m, st[un][tn][r]);
            m = fmaxf(m, __shfl_xor(m, 16));
            m = fmaxf(m, __shfl_xor(m, 32));
            mk[tn] = m * kE;
        }
        #pragma unroll
        for (int tn = 0; tn < 4; ++tn) {
            float s = 0.f;
            #pragma unroll
            for (int un = 0; un < 4; ++un)
                #pragma unroll
                for (int r = 0; r < 4; ++r) {
                    const float e = exp2f(fmaf(st[un][tn][r], kE, -mk[tn]));
                    st[un][tn][r] = e;
                    s += e;
                }
            s += __shfl_xor(s, 16);
            s += __shfl_xor(s, 32);
            rs[tn] = __builtin_amdgcn_rcpf(s);
        }

        f32x4 oa[2][4];
        #pragma unroll
        for (int dt = 0; dt < 2; ++dt)
            #pragma unroll
            for (int tn = 0; tn < 4; ++tn) oa[dt][tn] = (f32x4){0.f,0.f,0.f,0.f};

        #pragma unroll
        for (int half = 0; half < 2; ++half) {       // u-chunks of 32 (wave-private pl reuse)
            #pragma unroll
            for (int ub = 0; ub < 2; ++ub) {
                const int un = 2*half + ub;
                const int ul = ub*16 + 4*lg;
                #pragma unroll
                for (int tn = 0; tn < 4; ++tn) {
                    f16x4 ph = {(f16)st[un][tn][0], (f16)st[un][tn][1],
                                (f16)st[un][tn][2], (f16)st[un][tn][3]};
                    *(f16x4*)&pl[pidx(w, 16*tn + lr, ul)] = ph;
                }
            }
            f16x8 av[2];
            #pragma unroll
            for (int dt = 0; dt < 2; ++dt)
                av[dt] = *(const f16x8*)&vt[vidx(h, 16*dt + lr, half*32 + lg*8)];
            #pragma unroll
            for (int tn = 0; tn < 4; ++tn) {
                const f16x8 pb = *(const f16x8*)&pl[pidx(w, 16*tn + lr, lg*8)];
                #pragma unroll
                for (int dt = 0; dt < 2; ++dt)
                    oa[dt][tn] = MFMA16(av[dt], pb, oa[dt][tn], 0,0,0);
            }
        }
        // O epilogue -> osb[t][96] (vectorized; d-quad contiguous)
        #pragma unroll
        for (int tn = 0; tn < 4; ++tn) {
            const int t = 16*tn + lr;
            {
                f16x4 ov = {(f16)(oa[0][tn][0]*rs[tn]), (f16)(oa[0][tn][1]*rs[tn]),
                            (f16)(oa[0][tn][2]*rs[tn]), (f16)(oa[0][tn][3]*rs[tn])};
                *(f16x4*)&osb[t*96 + h*24 + 4*lg] = ov;
            }
            if (lg < 2) {                       // valid d = 16..23 only
                f16x4 ov = {(f16)(oa[1][tn][0]*rs[tn]), (f16)(oa[1][tn][1]*rs[tn]),
                            (f16)(oa[1][tn][2]*rs[tn]), (f16)(oa[1][tn][3]*rs[tn])};
                *(f16x4*)&osb[t*96 + h*24 + 16 + 4*lg] = ov;
            }
        }
    }
    __syncthreads();

    // ---- phase 3: outT[c][t] = sum_d pw[c][d] * O[t][d]; stage fp32 -> o2 (swizzled)
    {
        const int t = 16*w + lr;
        f16x8 bo[3];
        #pragma unroll
        for (int kk = 0; kk < 3; ++kk)
            bo[kk] = *(const f16x8*)&osb[t*96 + kk*32 + lg*8];
        #pragma unroll
        for (int n = 0; n < 6; ++n) {
            const int c = 16*n + lr;
            f32x4 pa = {0.f,0.f,0.f,0.f};
            #pragma unroll
            for (int kk = 0; kk < 3; ++kk) {
                const f16x8 aw = *(const f16x8*)(pw + c*96 + kk*32 + lg*8);
                pa = MFMA16(aw, bo[kk], pa, 0,0,0);
            }
            const int c0 = 16*n + 4*lg;
            const float4 b4 = *(const float4*)(proj_b + c0);
            f32x4 wv = {pa[0]+b4.x, pa[1]+b4.y, pa[2]+b4.z, pa[3]+b4.w};
            *(f32x4*)&o2[oidx(t, c0)] = wv;
        }
    }
    __syncthreads();

    // ---- coalesced fp32 store with window-reverse
    #pragma unroll
    for (int it = 0; it < 6; ++it) {
        const int i = it*256 + tid;
        const int t = i / 24, c4 = i - t*24;
        const float4 v = *(const float4*)&o2[oidx(t, c4*4)];
        *(float4*)(out + win_base + (size_t)(((t>>3)<<8) + (t&7))*96 + c4*4) = v;
    }
}

extern "C" void kernel_launch(void* const* d_in, const int* in_sizes, int n_in,
                              void* d_out, int out_size, void* d_ws, size_t ws_size,
                              hipStream_t stream) {
    const float* x      = (const float*)d_in[0];
    const float* qkv_w  = (const float*)d_in[1];
    const float* qkv_b  = (const float*)d_in[2];
    const float* proj_w = (const float*)d_in[3];
    const float* proj_b = (const float*)d_in[4];
    float* out = (float*)d_out;
    f16* ws = (f16*)d_ws;   // qw[27648] then pw[9216] fp16

    cvt_weights<<<dim3(144), dim3(256), 0, stream>>>(qkv_w, proj_w, ws);
    winattn<<<dim3(8192), dim3(256), SMEM_BYTES, stream>>>(x, ws, qkv_b, ws + 27648, proj_b, out);
}

// Round 5
// 218.136 us; speedup vs baseline: 1.4492x; 1.4492x over previous
//
#include <hip/hip_runtime.h>

// WindowAttention B=8 H=W=256 C=96 ws=8 heads=4 hd=24 — fp16 MFMA, zero-P-roundtrip.
// One block (4 waves) per window; wave = head in attention; permuted-u PV keeps P in regs.
// R4 fix: vt row stride 40 -> 64 (+XOR swizzle); vcol spans 0..63.

typedef _Float16 f16;
typedef f16 f16x8 __attribute__((ext_vector_type(8)));
typedef f16 f16x4 __attribute__((ext_vector_type(4)));
typedef float f32x4 __attribute__((ext_vector_type(4)));

#define MFMA16 __builtin_amdgcn_mfma_f32_16x16x32_f16

__global__ void cvt_weights(const float* __restrict__ qkv_w,
                            const float* __restrict__ proj_w,
                            f16* __restrict__ ws) {
    int i = blockIdx.x * 256 + threadIdx.x;
    if (i < 27648)      ws[i] = (f16)qkv_w[i];
    else if (i < 36864) ws[i] = (f16)proj_w[i - 27648];
}

// XOR swizzle for 128-wide f16 rows: flips f16-idx bits 3..5, 2-way max on frag reads.
__device__ __forceinline__ int qidx(int t, int o)      { return t*128 + (o ^ ((t & 7) << 3)); }
// vt rows are 64 f16 wide, same XOR trick.
__device__ __forceinline__ int vtidx(int row, int col) { return row*64 + (col ^ ((row & 7) << 3)); }

__global__ __launch_bounds__(256, 3) void winattn(
    const float* __restrict__ x,
    const f16*   __restrict__ qw,      // [288][96] fp16
    const float* __restrict__ qkv_b,   // [288]
    const f16*   __restrict__ pw,      // [96][96] fp16
    const float* __restrict__ proj_b,  // [96]
    float* __restrict__ out)
{
    __shared__ __align__(16) f16 qq[64*128];   // q [t][h*32+d] swizzled; reused as O [t][c] after B2
    __shared__ __align__(16) f16 qk_[64*128];  // k [t][h*32+d] swizzled
    __shared__ __align__(16) f16 vt[4*24*64];  // v^T [h][d][perm-u 0..63], swizzled

    const int tid = threadIdx.x;
    const int wid = blockIdx.x;
    const int bb = wid >> 10, wh = (wid >> 5) & 31, ww = wid & 31;
    const size_t win_base = ((size_t)(bb*256 + wh*8)*256 + (size_t)(ww*8)) * 96;

    const int lane = tid & 63, w = tid >> 6;
    const int lr = lane & 15, lg = lane >> 4;
    const int t = 16*w + lr;                          // this lane's token (phases 1,3)
    const size_t tok_off = win_base + (size_t)(((t>>3)<<8) + (t&7))*96;

    // ---- zero K-pads d=24..31 of qq/qk (read by K=32 S-MFMA)
    {
        const f16x8 z8 = {0,0,0,0,0,0,0,0};
        const int tz = tid >> 2, hz = tid & 3;
        *(f16x8*)&qq[qidx(tz, hz*32 + 24)] = z8;
        *(f16x8*)&qk_[qidx(tz, hz*32 + 24)] = z8;
    }

    // ---- phase 1: QKV^T.  A = qkv_w rows (global), B = x tokens (global->regs).
    f16x8 ax[3];
    #pragma unroll
    for (int kk = 0; kk < 3; ++kk) {
        const float* xp = x + tok_off + kk*32 + lg*8;
        const float4 u0 = *(const float4*)xp;
        const float4 u1 = *(const float4*)(xp + 4);
        f16x8 a;
        a[0]=(f16)u0.x; a[1]=(f16)u0.y; a[2]=(f16)u0.z; a[3]=(f16)u0.w;
        a[4]=(f16)u1.x; a[5]=(f16)u1.y; a[6]=(f16)u1.z; a[7]=(f16)u1.w;
        ax[kk] = a;
    }
    // permuted v^T column for this lane's token t (u_k such that perm(u_k) = t)
    const int vcol = (w>>1)*32 + (lr>>2)*8 + (w&1)*4 + (lr&3);

    #pragma unroll
    for (int n = 0; n < 18; ++n) {
        const int j = 16*n + lr;
        f32x4 acc = {0.f,0.f,0.f,0.f};
        #pragma unroll
        for (int kk = 0; kk < 3; ++kk)
            acc = MFMA16(*(const f16x8*)(qw + j*96 + kk*32 + lg*8), ax[kk], acc, 0,0,0);
        const int j0 = 16*n + 4*lg;                   // this lane holds channels j0..j0+3 of token t
        const float4 b4 = *(const float4*)(qkv_b + j0);
        const float v0 = acc[0]+b4.x, v1 = acc[1]+b4.y, v2 = acc[2]+b4.z, v3 = acc[3]+b4.w;
        if (n < 6) {                                  // q -> head-padded
            const int h = j0 / 24, d0 = j0 - 24*h;
            f16x4 hv = {(f16)v0,(f16)v1,(f16)v2,(f16)v3};
            *(f16x4*)&qq[qidx(t, h*32 + d0)] = hv;
        } else if (n < 12) {                          // k -> head-padded
            const int jk = j0 - 96;
            const int h = jk / 24, d0 = jk - 24*h;
            f16x4 hv = {(f16)v0,(f16)v1,(f16)v2,(f16)v3};
            *(f16x4*)&qk_[qidx(t, h*32 + d0)] = hv;
        } else {                                      // v -> v^T with permuted u-columns
            const int jv = j0 - 192;
            const int h = jv / 24, d0 = jv - 24*h;
            vt[vtidx(h*24 + d0+0, vcol)] = (f16)v0;
            vt[vtidx(h*24 + d0+1, vcol)] = (f16)v1;
            vt[vtidx(h*24 + d0+2, vcol)] = (f16)v2;
            vt[vtidx(h*24 + d0+3, vcol)] = (f16)v3;
        }
    }
    __syncthreads();   // B1: q/k/v staged

    // ---- phase 2: wave = head h.  S^T = mfma(K, Q); in-reg softmax; O^T = mfma(V^T, P-in-reg).
    const int h = w;
    f16x8 bf[4];
    #pragma unroll
    for (int i = 0; i < 4; ++i)
        bf[i] = *(const f16x8*)&qq[qidx(16*i + lr, h*32 + lg*8)];
    __syncthreads();   // B2: all qq reads done -> qq reusable as O staging

    f16x8 af[4];
    #pragma unroll
    for (int i = 0; i < 4; ++i)
        af[i] = *(const f16x8*)&qk_[qidx(16*i + lr, h*32 + lg*8)];

    f32x4 st[4][4];    // st[un][tn]: value for u=16un+4lg+r, t=16tn+lr
    #pragma unroll
    for (int un = 0; un < 4; ++un)
        #pragma unroll
        for (int tn = 0; tn < 4; ++tn)
            st[un][tn] = MFMA16(af[un], bf[tn], (f32x4){0.f,0.f,0.f,0.f}, 0,0,0);

    const float kE = 0.29448890f;   // 24^-0.5 * log2(e)
    float rs[4];
    #pragma unroll
    for (int tn = 0; tn < 4; ++tn) {
        float m = st[0][tn][0];
        #pragma unroll
        for (int un = 0; un < 4; ++un)
            #pragma unroll
            for (int r = 0; r < 4; ++r) m = fmaxf(m, st[un][tn][r]);
        m = fmaxf(m, __shfl_xor(m, 16));
        m = fmaxf(m, __shfl_xor(m, 32));
        const float mk = m * kE;
        float s = 0.f;
        #pragma unroll
        for (int un = 0; un < 4; ++un)
            #pragma unroll
            for (int r = 0; r < 4; ++r) {
                const float e = exp2f(fmaf(st[un][tn][r], kE, -mk));
                st[un][tn][r] = e;
                s += e;
            }
        s += __shfl_xor(s, 16);
        s += __shfl_xor(s, 32);
        rs[tn] = 1.f / s;
    }

    // PV with permuted u: B-frag = this lane's own st values (no shuffle, no LDS).
    f32x4 oa0[4], oa1[4];
    #pragma unroll
    for (int tn = 0; tn < 4; ++tn) {
        oa0[tn] = (f32x4){0.f,0.f,0.f,0.f};
        oa1[tn] = (f32x4){0.f,0.f,0.f,0.f};
    }
    const int d1 = (16 + lr > 23) ? 23 : 16 + lr;     // clamp: output rows d>=24 discarded
    #pragma unroll
    for (int hf = 0; hf < 2; ++hf) {
        const f16x8 av0 = *(const f16x8*)&vt[vtidx(h*24 + lr, hf*32 + lg*8)];
        const f16x8 av1 = *(const f16x8*)&vt[vtidx(h*24 + d1, hf*32 + lg*8)];
        #pragma unroll
        for (int tn = 0; tn < 4; ++tn) {
            f16x8 pb;
            pb[0]=(f16)st[2*hf  ][tn][0]; pb[1]=(f16)st[2*hf  ][tn][1];
            pb[2]=(f16)st[2*hf  ][tn][2]; pb[3]=(f16)st[2*hf  ][tn][3];
            pb[4]=(f16)st[2*hf+1][tn][0]; pb[5]=(f16)st[2*hf+1][tn][1];
            pb[6]=(f16)st[2*hf+1][tn][2]; pb[7]=(f16)st[2*hf+1][tn][3];
            oa0[tn] = MFMA16(av0, pb, oa0[tn], 0,0,0);
            oa1[tn] = MFMA16(av1, pb, oa1[tn], 0,0,0);
        }
    }
    // O epilogue -> qq reused as osb[t][c] (c = h*24 + d), vectorized b64 writes
    #pragma unroll
    for (int tn = 0; tn < 4; ++tn) {
        const int tt = 16*tn + lr;
        f16x4 o0 = {(f16)(oa0[tn][0]*rs[tn]), (f16)(oa0[tn][1]*rs[tn]),
                    (f16)(oa0[tn][2]*rs[tn]), (f16)(oa0[tn][3]*rs[tn])};
        *(f16x4*)&qq[qidx(tt, h*24 + 4*lg)] = o0;     // d = 4lg+r (0..15)
        if (lg < 2) {                                 // d = 16+4lg+r (16..23)
            f16x4 o1 = {(f16)(oa1[tn][0]*rs[tn]), (f16)(oa1[tn][1]*rs[tn]),
                        (f16)(oa1[tn][2]*rs[tn]), (f16)(oa1[tn][3]*rs[tn])};
            *(f16x4*)&qq[qidx(tt, h*24 + 16 + 4*lg)] = o1;
        }
    }
    __syncthreads();   // B3: O complete

    // ---- phase 3: out^T = mfma(proj_w rows, O tokens); direct float4 global stores
    f16x8 bo[3];
    #pragma unroll
    for (int kk = 0; kk < 3; ++kk)
        bo[kk] = *(const f16x8*)&qq[qidx(t, kk*32 + lg*8)];
    #pragma unroll
    for (int n = 0; n < 6; ++n) {
        const int c = 16*n + lr;
        f32x4 pa = {0.f,0.f,0.f,0.f};
        #pragma unroll
        for (int kk = 0; kk < 3; ++kk)
            pa = MFMA16(*(const f16x8*)(pw + c*96 + kk*32 + lg*8), bo[kk], pa, 0,0,0);
        const int c0 = 16*n + 4*lg;                   // lane holds out[t][c0..c0+3]
        const float4 b4 = *(const float4*)(proj_b + c0);
        float4 ov = {pa[0]+b4.x, pa[1]+b4.y, pa[2]+b4.z, pa[3]+b4.w};
        *(float4*)(out + tok_off + c0) = ov;
    }
}

extern "C" void kernel_launch(void* const* d_in, const int* in_sizes, int n_in,
                              void* d_out, int out_size, void* d_ws, size_t ws_size,
                              hipStream_t stream) {
    const float* x      = (const float*)d_in[0];
    const float* qkv_w  = (const float*)d_in[1];
    const float* qkv_b  = (const float*)d_in[2];
    const float* proj_w = (const float*)d_in[3];
    const float* proj_b = (const float*)d_in[4];
    float* out = (float*)d_out;
    f16* ws = (f16*)d_ws;   // qw[27648] then pw[9216] fp16

    cvt_weights<<<dim3(144), dim3(256), 0, stream>>>(qkv_w, proj_w, ws);
    winattn<<<dim3(8192), dim3(256), 0, stream>>>(x, ws, qkv_b, ws + 27648, proj_b, out);
}